// Round 13
// baseline (626.015 us; speedup 1.0000x reference)
//
#include <hip/hip_runtime.h>
#include <hip/hip_bf16.h>
#include <cstdint>

// Problem constants (match setup_inputs)
constexpr int B  = 2;
constexpr int L  = 2048;
constexpr int S  = 2048;
constexpr int DM = 1024;
constexpr int H  = 16;
constexpr int R  = 32;     // rank
constexpr int DH = 64;     // head dim
constexpr int TOPK = 32;
constexpr int SELCAP = 36;
constexpr float SCALE = 0.17677669529663687f; // 1/sqrt(32)

// MEASURED (R4-R12): backend VGPR cap = LDS-implied max-blocks occupancy
// (64KB->2blk->128cap; >40KB->3blk->~85cap; <=40KB->4blk->64cap). Demand over
// cap = scratch spill = GB-scale HBM traffic. LICM hoists loop-invariant LDS
// reads -> defeat with opaque-zero asm (R9). R13: half-split selection
// (top-32 decomposes over halves) shrinks score LDS 64->32KB; LDS padded to
// 41.5KB to pin the 3-block/85-VGPR budget (4-block/64 would risk spill).

using short8 = __attribute__((ext_vector_type(8))) short;
using f32x4  = __attribute__((ext_vector_type(4))) float;

__device__ __forceinline__ unsigned short bf16_rne(float x) {
    unsigned int u = __float_as_uint(x);
    unsigned int r = u + 0x7FFFu + ((u >> 16) & 1u);
    return (unsigned short)(r >> 16);
}

// ---------------------------------------------------------------------------
// Merged Q/K projection (R12-proven, bit-identical outputs).
// ---------------------------------------------------------------------------
__global__ __launch_bounds__(256, 2)
void qk_proj(const float* __restrict__ Aq, const float* __restrict__ Wq_,
             const float* __restrict__ bq_, float* __restrict__ Cq,
             const float* __restrict__ Ak, const float* __restrict__ Wk_,
             const float* __restrict__ bk_, float* __restrict__ Ck,
             int M, int N, int K)
{
    const int z = blockIdx.z;
    const float* A    = z ? Ak  : Aq;
    const float* W    = z ? Wk_ : Wq_;
    const float* bias = z ? bk_ : bq_;
    float*       C    = z ? Ck  : Cq;
    const float outScale = z ? 1.0f : SCALE;

    __shared__ float As[16][136];
    __shared__ float Ws[16][132];

    const int t  = threadIdx.x;
    const int tx = t & 15;
    const int ty = t >> 4;
    const int m0 = blockIdx.y * 128;
    const int n0 = blockIdx.x * 128;

    float acc[8][8];
#pragma unroll
    for (int i = 0; i < 8; ++i)
#pragma unroll
        for (int j = 0; j < 8; ++j) acc[i][j] = 0.f;

    for (int kb = 0; kb < K; kb += 16) {
        __syncthreads();
#pragma unroll
        for (int it = 0; it < 2; ++it) {
            int f4  = t + it * 256;
            int row = f4 >> 2;
            int cg  = (f4 & 3) * 4;
            float4 av = *(const float4*)&A[(size_t)(m0 + row) * K + kb + cg];
            As[cg + 0][row] = av.x;
            As[cg + 1][row] = av.y;
            As[cg + 2][row] = av.z;
            As[cg + 3][row] = av.w;
        }
#pragma unroll
        for (int it = 0; it < 2; ++it) {
            int f4 = t + it * 256;
            int kk = f4 >> 5;
            int cb = (f4 & 31) * 4;
            *(float4*)&Ws[kk][cb] = *(const float4*)&W[(size_t)(kb + kk) * N + n0 + cb];
        }
        __syncthreads();
#pragma unroll
        for (int kk = 0; kk < 16; ++kk) {
            float4 a0 = *(const float4*)&As[kk][ty * 8];
            float4 a1 = *(const float4*)&As[kk][ty * 8 + 4];
            float4 w0 = *(const float4*)&Ws[kk][tx * 8];
            float4 w1 = *(const float4*)&Ws[kk][tx * 8 + 4];
            float a[8] = {a0.x, a0.y, a0.z, a0.w, a1.x, a1.y, a1.z, a1.w};
            float w[8] = {w0.x, w0.y, w0.z, w0.w, w1.x, w1.y, w1.z, w1.w};
#pragma unroll
            for (int i = 0; i < 8; ++i)
#pragma unroll
                for (int j = 0; j < 8; ++j)
                    acc[i][j] = fmaf(a[i], w[j], acc[i][j]);
        }
    }

    float4 b0 = *(const float4*)&bias[n0 + tx * 8];
    float4 b1 = *(const float4*)&bias[n0 + tx * 8 + 4];
#pragma unroll
    for (int i = 0; i < 8; ++i) {
        float4 o0 = make_float4((acc[i][0] + b0.x) * outScale, (acc[i][1] + b0.y) * outScale,
                                (acc[i][2] + b0.z) * outScale, (acc[i][3] + b0.w) * outScale);
        float4 o1 = make_float4((acc[i][4] + b1.x) * outScale, (acc[i][5] + b1.y) * outScale,
                                (acc[i][6] + b1.z) * outScale, (acc[i][7] + b1.w) * outScale);
        size_t off = (size_t)(m0 + ty * 8 + i) * N + n0 + tx * 8;
        *(float4*)&C[off]     = o0;
        *(float4*)&C[off + 4] = o1;
    }
}

// ---------------------------------------------------------------------------
// Dual transpose + split (R12-proven).
// ---------------------------------------------------------------------------
__global__ __launch_bounds__(256)
void transpose_split_dual(const float* __restrict__ Wv_, unsigned short* __restrict__ VhT,
                          unsigned short* __restrict__ VlT,
                          const float* __restrict__ Wo_, unsigned short* __restrict__ OhT,
                          unsigned short* __restrict__ OlT, int N, int K)
{
    const int z = blockIdx.z;
    const float* W = z ? Wo_ : Wv_;
    unsigned short* Th = z ? OhT : VhT;
    unsigned short* Tl = z ? OlT : VlT;

    __shared__ float tile[32][33];
    const int n0 = blockIdx.x * 32;
    const int k0 = blockIdx.y * 32;
    const int tx = threadIdx.x & 31;
    const int ty = threadIdx.x >> 5;

#pragma unroll
    for (int i = ty; i < 32; i += 8)
        tile[i][tx] = W[(size_t)(k0 + i) * N + n0 + tx];
    __syncthreads();
#pragma unroll
    for (int i = ty; i < 32; i += 8) {
        float x = tile[tx][i];
        unsigned short h = bf16_rne(x);
        float hf = __uint_as_float((unsigned int)h << 16);
        unsigned short l = bf16_rne(x - hf);
        Th[(size_t)(n0 + i) * K + k0 + tx] = h;
        Tl[(size_t)(n0 + i) * K + k0 + tx] = l;
    }
}

// ---------------------------------------------------------------------------
// Split-bf16 MFMA GEMM (R11-proven).
// ---------------------------------------------------------------------------
__global__ __launch_bounds__(256, 1)
void gemm_mfma_split(const float* __restrict__ A, const unsigned short* __restrict__ Bh,
                     const unsigned short* __restrict__ Bl, const float* __restrict__ bias,
                     float* __restrict__ C, int M, int N, int K)
{
    constexpr int LDT = 56;
    __shared__ unsigned short Ah[128 * LDT];
    __shared__ unsigned short Al[128 * LDT];
    __shared__ unsigned short Wh[128 * LDT];
    __shared__ unsigned short Wl[128 * LDT];

    const int t    = threadIdx.x;
    const int lane = t & 63;
    const int w    = t >> 6;
    const int wr   = w >> 1;
    const int wc   = w & 1;
    const int l15  = lane & 15;
    const int l4   = lane >> 4;
    const int m0   = blockIdx.y * 128;
    const int n0   = blockIdx.x * 128;

    f32x4 acc[4][4];
#pragma unroll
    for (int m = 0; m < 4; ++m)
#pragma unroll
        for (int n = 0; n < 4; ++n) {
            f32x4 z = {0.f, 0.f, 0.f, 0.f};
            acc[m][n] = z;
        }

#pragma unroll 1
    for (int kb = 0; kb < K; kb += 32) {
        __syncthreads();
#pragma unroll
        for (int it = 0; it < 4; ++it) {
            int f   = t + it * 256;
            int row = f >> 3;
            int kg  = (f & 7) * 4;
            float4 av = *(const float4*)&A[(size_t)(m0 + row) * K + kb + kg];
            ushort4 hv, lv;
            hv.x = bf16_rne(av.x); lv.x = bf16_rne(av.x - __uint_as_float((unsigned int)hv.x << 16));
            hv.y = bf16_rne(av.y); lv.y = bf16_rne(av.y - __uint_as_float((unsigned int)hv.y << 16));
            hv.z = bf16_rne(av.z); lv.z = bf16_rne(av.z - __uint_as_float((unsigned int)hv.z << 16));
            hv.w = bf16_rne(av.w); lv.w = bf16_rne(av.w - __uint_as_float((unsigned int)hv.w << 16));
            *(ushort4*)&Ah[row * LDT + kg] = hv;
            *(ushort4*)&Al[row * LDT + kg] = lv;
            ushort4 bh4 = *(const ushort4*)&Bh[(size_t)(n0 + row) * K + kb + kg];
            ushort4 bl4 = *(const ushort4*)&Bl[(size_t)(n0 + row) * K + kb + kg];
            *(ushort4*)&Wh[row * LDT + kg] = bh4;
            *(ushort4*)&Wl[row * LDT + kg] = bl4;
        }
        __syncthreads();

        short8 ah[4], al[4], bh[4], bl[4];
#pragma unroll
        for (int m = 0; m < 4; ++m) {
            int row = wr * 64 + m * 16 + l15;
            ah[m] = *(short8*)&Ah[row * LDT + l4 * 8];
            al[m] = *(short8*)&Al[row * LDT + l4 * 8];
        }
#pragma unroll
        for (int n = 0; n < 4; ++n) {
            int col = wc * 64 + n * 16 + l15;
            bh[n] = *(short8*)&Wh[col * LDT + l4 * 8];
            bl[n] = *(short8*)&Wl[col * LDT + l4 * 8];
        }
#pragma unroll
        for (int m = 0; m < 4; ++m)
#pragma unroll
            for (int n = 0; n < 4; ++n)
                acc[m][n] = __builtin_amdgcn_mfma_f32_16x16x32_bf16(ah[m], bh[n], acc[m][n], 0, 0, 0);
#pragma unroll
        for (int m = 0; m < 4; ++m)
#pragma unroll
            for (int n = 0; n < 4; ++n)
                acc[m][n] = __builtin_amdgcn_mfma_f32_16x16x32_bf16(ah[m], bl[n], acc[m][n], 0, 0, 0);
#pragma unroll
        for (int m = 0; m < 4; ++m)
#pragma unroll
            for (int n = 0; n < 4; ++n)
                acc[m][n] = __builtin_amdgcn_mfma_f32_16x16x32_bf16(al[m], bh[n], acc[m][n], 0, 0, 0);
    }

#pragma unroll
    for (int m = 0; m < 4; ++m) {
        int row = m0 + wr * 64 + m * 16 + l4 * 4;
#pragma unroll
        for (int n = 0; n < 4; ++n) {
            int col = n0 + wc * 64 + n * 16 + l15;
            float bv = bias[col];
#pragma unroll
            for (int r = 0; r < 4; ++r)
                C[(size_t)(row + r) * N + col] = acc[m][n][r] + bv;
        }
    }
}

// ---------------------------------------------------------------------------
// Fused score + HALF-SPLIT exact top-k + softmax + PV gather.
// Score FMA chains identical to R9-R12 (bit-identical scores).
// Selection decomposed: top-32(row) subset of top-32(half0) U top-32(half1);
// the count predicate cnt(>=T)>=32 is equal on candidates vs full row for all
// T, so the radix threshold P is bit-identical; emission order (j asc, lane
// asc, half0 then half1) equals the old j=0..31 order -> gather bit-identical.
// Only dsum's reduction partition differs (~1e-7 relative, inside slack).
// Score LDS 32KB; total padded to ~41.5KB -> backend targets 3 blocks/CU ->
// 85-VGPR cap (demand ~70, no spill) -> 24 waves/CU vs R12's 16.
// ---------------------------------------------------------------------------
__global__ __launch_bounds__(512, 1)
void score_select_gather(const float* __restrict__ Qp, const float* __restrict__ Kp,
                         const float* __restrict__ Vp, float* __restrict__ Oh)
{
    __shared__ float  sclds[8][1024];          // 32 KB (one half of scores)
    __shared__ float4 Qlds4[8][8];             // 1 KB
    __shared__ unsigned int   candU[8][160];   // 5 KB  (sortable scores, 2 halves x up to 40 + pad)
    __shared__ unsigned short candI[8][160];   // 2.5 KB (key indices)
    // total ~40.5-41.5 KB -> 3 blocks/CU budget

    const int t    = threadIdx.x;
    const int lane = t & 63;
    const int wv   = t >> 6;            // 0..7

    const int wgid = blockIdx.x;
    const int xcd  = wgid & 7;
    const int jj   = wgid >> 3;              // 0..1023
    const int bh   = xcd + 8 * (jj >> 8);    // 0..31
    const int tile = jj & 255;
    const int b    = bh >> 4;
    const int h    = bh & 15;
    const int lbase = tile * 8;

    const float* kbase = Kp + (size_t)b * S * (H * R) + h * R;
    const float* qbase = Qp + (size_t)(b * L + lbase) * (H * R) + h * R;

    if (t < 64) {
        int row = t >> 3, q = t & 7;
        Qlds4[row][q] = *(const float4*)(qbase + (size_t)row * (H * R) + q * 4);
    }
    __syncthreads();

    // score one half (2 chunks of 512 keys) into sclds[.][0..1023]
    auto score_half = [&](int hf) {
#pragma unroll 1
        for (int cc = 0; cc < 2; ++cc) {
            const int c = hf * 2 + cc;
            float4 ka[8];
            const float* kp = kbase + (size_t)(c * 512 + wv * 64 + lane) * (H * R);
#pragma unroll
            for (int q = 0; q < 8; ++q) ka[q] = *(const float4*)(kp + q * 4);

            int zero;
            asm volatile("v_mov_b32 %0, 0" : "=v"(zero));   // anti-LICM (R9)

            const int keyl = cc * 512 + wv * 64 + lane;
#pragma unroll
            for (int r = 0; r < 8; ++r) {
                const float4* qrow = Qlds4[r + zero];
                float s = 0.f;
#pragma unroll
                for (int q = 0; q < 8; ++q) {
                    float4 qv = qrow[q];
                    s = fmaf(qv.x, ka[q].x, s);
                    s = fmaf(qv.y, ka[q].y, s);
                    s = fmaf(qv.z, ka[q].z, s);
                    s = fmaf(qv.w, ka[q].w, s);
                }
                sclds[r][keyl] = s;
            }
        }
    };

    const unsigned long long lanelt = (1ull << lane) - 1ull;
    const int r = wv;                 // this wave's row
    float mxA = 0.f;
    int   cntA = 0;

    // half-select: radix top-32 of sclds[r][0..1023], compact (u,idx) to cand
    // slot base so*40. Returns count; max into *mx.
    auto half_select = [&](int hf, int so, float* mxp) -> int {
        float sreg[16];
#pragma unroll
        for (int j = 0; j < 16; ++j) sreg[j] = sclds[r][j * 64 + lane];

        float m = sreg[0];
#pragma unroll
        for (int j = 1; j < 16; ++j) m = fmaxf(m, sreg[j]);
#pragma unroll
        for (int off = 32; off >= 1; off >>= 1)
            m = fmaxf(m, __shfl_xor(m, off, 64));
        *mxp = m;

        unsigned int u[16];
#pragma unroll
        for (int j = 0; j < 16; ++j) {
            unsigned int bb  = __float_as_uint(sreg[j]);
            unsigned int sgn = (unsigned int)(((int)bb) >> 31);
            u[j] = bb ^ (sgn | 0x80000000u);
        }

        unsigned int P = 0;
        for (int bit = 31; bit >= 0; --bit) {
            unsigned int test = P | (1u << bit);
            int c2 = 0;
#pragma unroll
            for (int j = 0; j < 16; ++j)
                c2 += (int)__popcll(__ballot(u[j] >= test));
            if (c2 >= TOPK) {
                P = test;
                if (c2 == TOPK) break;
            }
        }

        int base = 0;
#pragma unroll
        for (int j = 0; j < 16; ++j) {
            bool sel = (u[j] >= P);
            unsigned long long mm = __ballot(sel);
            if (sel) {
                int pos = base + (int)__popcll(mm & lanelt);
                if (pos < 40) {
                    candU[r][so + pos] = u[j];
                    candI[r][so + pos] = (unsigned short)(hf * 1024 + j * 64 + lane);
                }
            }
            base += (int)__popcll(mm);
        }
        return base < 40 ? base : 40;
    };

    score_half(0);
    __syncthreads();
    cntA = half_select(0, 0, &mxA);
    __syncthreads();                  // sel reads done before overwrite
    score_half(1);
    __syncthreads();

    {
        float mxB;
        int cntB = half_select(1, 40, &mxB);
        const float mx = fmaxf(mxA, mxB);

        // final radix over <=80 candidates (2 per lane, validity-masked)
        const bool v0 = lane < cntA;
        const bool v1 = lane < cntB;
        const unsigned int u0 = v0 ? candU[r][lane]      : 0u;
        const unsigned int u1 = v1 ? candU[r][40 + lane] : 0u;

        unsigned int P = 0;
        for (int bit = 31; bit >= 0; --bit) {
            unsigned int test = P | (1u << bit);
            int c2 = (int)__popcll(__ballot(v0 && u0 >= test))
                   + (int)__popcll(__ballot(v1 && u1 >= test));
            if (c2 >= TOPK) {
                P = test;
                if (c2 == TOPK) break;
            }
        }

        // final compact in storage order (A slots by lane, then B slots):
        // equals global j-asc/lane-asc order -> same emission as R12.
        float part = 0.f;
        int baseF;
        {
            bool s0 = v0 && (u0 >= P);
            unsigned long long m0 = __ballot(s0);
            if (s0) {
                unsigned int sg2  = (unsigned int)(((int)u0) >> 31);
                unsigned int mask = 0x80000000u | ~sg2;
                float f0 = __uint_as_float(u0 ^ mask);
                float e0 = __expf(f0 - mx);
                int pos = (int)__popcll(m0 & lanelt);
                sclds[r][pos]       = e0;
                sclds[r][512 + pos] = __uint_as_float((unsigned int)candI[r][lane]);
                part += e0;
            }
            baseF = (int)__popcll(m0);
            bool s1 = v1 && (u1 >= P);
            unsigned long long m1 = __ballot(s1);
            if (s1) {
                unsigned int sg2  = (unsigned int)(((int)u1) >> 31);
                unsigned int mask = 0x80000000u | ~sg2;
                float f1 = __uint_as_float(u1 ^ mask);
                float e1 = __expf(f1 - mx);
                int pos = baseF + (int)__popcll(m1 & lanelt);
                sclds[r][pos]       = e1;
                sclds[r][512 + pos] = __uint_as_float((unsigned int)candI[r][40 + lane]);
                part += e1;
            }
            baseF += (int)__popcll(m1);
        }
        float dsum = part;
#pragma unroll
        for (int off = 32; off >= 1; off >>= 1)
            dsum += __shfl_xor(dsum, off, 64);

        // ---- PV gather (exact R12 summation order) ----
        const int cn = baseF < SELCAP ? baseF : SELCAP;
        const float inv = 1.0f / dsum;
        const float* vb = Vp + (size_t)b * S * DM + h * DH + lane;

        float a0 = 0.f, a1 = 0.f, a2 = 0.f, a3 = 0.f;
        int tt = 0;
        for (; tt + 4 <= cn; tt += 4) {
            int   s0 = (int)__float_as_uint(sclds[r][512 + tt + 0]);
            int   s1 = (int)__float_as_uint(sclds[r][512 + tt + 1]);
            int   s2 = (int)__float_as_uint(sclds[r][512 + tt + 2]);
            int   s3 = (int)__float_as_uint(sclds[r][512 + tt + 3]);
            float w0 = sclds[r][tt + 0], w1 = sclds[r][tt + 1];
            float w2 = sclds[r][tt + 2], w3 = sclds[r][tt + 3];
            a0 = fmaf(w0, vb[(size_t)s0 * DM], a0);
            a1 = fmaf(w1, vb[(size_t)s1 * DM], a1);
            a2 = fmaf(w2, vb[(size_t)s2 * DM], a2);
            a3 = fmaf(w3, vb[(size_t)s3 * DM], a3);
        }
        for (; tt < cn; ++tt) {
            int s0 = (int)__float_as_uint(sclds[r][512 + tt]);
            a0 = fmaf(sclds[r][tt], vb[(size_t)s0 * DM], a0);
        }
        Oh[(size_t)(b * L + lbase + r) * DM + h * DH + lane] = ((a0 + a1) + (a2 + a3)) * inv;
    }
}

// ---------------------------------------------------------------------------
extern "C" void kernel_launch(void* const* d_in, const int* in_sizes, int n_in,
                              void* d_out, int out_size, void* d_ws, size_t ws_size,
                              hipStream_t stream)
{
    const float* q  = (const float*)d_in[0];
    const float* k  = (const float*)d_in[1];
    const float* v  = (const float*)d_in[2];
    const float* Wq = (const float*)d_in[3];
    const float* bq = (const float*)d_in[4];
    const float* Wk = (const float*)d_in[5];
    const float* bk = (const float*)d_in[6];
    const float* Wv = (const float*)d_in[7];
    const float* bv = (const float*)d_in[8];
    const float* Wo = (const float*)d_in[9];
    const float* bo = (const float*)d_in[10];
    // d_in[11] = pos_bias: per-head additive constant -> top-k/softmax invariant -> no-op.

    float* out = (float*)d_out;
    char*  ws  = (char*)d_ws;

    const size_t MB = 1024 * 1024;
    float* Qp = (float*)(ws);             //  8 MiB (pre-scaled Q)
    float* Kp = (float*)(ws + 8  * MB);   //  8 MiB
    float* Vp = (float*)(ws + 16 * MB);   // 16 MiB
    float* Oh = (float*)(ws + 32 * MB);   // 16 MiB
    unsigned short* WvH = (unsigned short*)(ws + 48 * MB);
    unsigned short* WvL = (unsigned short*)(ws + 50 * MB);
    unsigned short* WoH = (unsigned short*)(ws + 52 * MB);
    unsigned short* WoL = (unsigned short*)(ws + 54 * MB);

    const int M = B * L;  // 4096
    dim3 blk(256);

    transpose_split_dual<<<dim3(DM / 32, DM / 32, 2), blk, 0, stream>>>(
        Wv, WvH, WvL, Wo, WoH, WoL, DM, DM);

    gemm_mfma_split<<<dim3(DM / 128, M / 128), blk, 0, stream>>>(v, WvH, WvL, bv, Vp, M, DM, DM);

    qk_proj<<<dim3((H * R) / 128, M / 128, 2), blk, 0, stream>>>(
        q, Wq, bq, Qp, k, Wk, bk, Kp, M, H * R, DM);

    score_select_gather<<<dim3(8192), dim3(512), 0, stream>>>(Qp, Kp, Vp, Oh);

    gemm_mfma_split<<<dim3(DM / 128, M / 128), blk, 0, stream>>>(Oh, WoH, WoL, bo, out, M, DM, DM);
}